// Round 5
// baseline (54291.858 us; speedup 1.0000x reference)
//
#include <hip/hip_runtime.h>
#include <math.h>

#define L_SEQ 8192
#define I_DIM 256
#define H_DIM 2048
#define NWG0  64          // layer-0: 64 WGs x 32 rows (16 thr/row)
#define NWG1  128         // layer-1: 128 WGs x 16 rows (32 thr/row)
#define NWG   (NWG0 + NWG1)
#define TPB   512

// ws layout (bytes): [0] runctr | [256..1024) start-barrier slots
//   [4096) h0 ring: 8 slots x 32 KB (channel-spread) | [+256K) h1 ring: same.
//
// Channel-spread layout: within a slot, 128-B chunk c128 (= row/32, 0..63) lives
// at page (c128&7)*4KB + (c128>>3)*128B. Each wave's 1-KB poll touches 8 distinct
// 4-KB pages -> ~8 MALL channels instead of 1-2; slots at 32-KB stride rotate the
// channel set. Kills the coherence-point hotspot of a contiguous 8-KB vector.
//
// Self-tagged dataflow (proven rounds 3-4): value = h + ctr(step), ctr = 4 +
// 8*((step>>3)&1), ring depth 8, valid iff |v-ctr|<=1. Poison (0xAA) and the
// 0.0f invalidation marker never match. Ring-overwrite safety: intra-layer by
// full-vector validation (spread <= 5 < 8); cross-layer by L0's sentinel
// throttle on h1_{s-5} (one row per L1 WG), run off the serial path.
//
// Weights live in AGPRs (v_accvgpr_write at init, v_accvgpr_read per use):
// L0 144 + L1 128 AGPR + ~90 arch VGPR fits the 256/wave budget at 2 waves/SIMD.

__device__ __forceinline__ int h_off(int slot, int row) {
  return slot * 8192 + ((row >> 5) & 7) * 1024 + (row >> 8) * 32 + (row & 31);
}

__device__ __forceinline__ void cstore1(float* p, float v) {
  asm volatile("global_store_dword %0, %1, off sc0 sc1" :: "v"(p), "v"(v) : "memory");
}
__device__ __forceinline__ void cstoreu(unsigned* p, unsigned v) {
  asm volatile("global_store_dword %0, %1, off sc0 sc1" :: "v"(p), "v"(v) : "memory");
}
__device__ __forceinline__ float cload1(const float* p) {
  float v;
  asm volatile("global_load_dword %0, %1, off sc0 sc1\n\ts_waitcnt vmcnt(0)"
               : "=v"(v) : "v"(p) : "memory");
  return v;
}
__device__ __forceinline__ unsigned cloadu(const unsigned* p) {
  unsigned v;
  asm volatile("global_load_dword %0, %1, off sc0 sc1\n\ts_waitcnt vmcnt(0)"
               : "=v"(v) : "v"(p) : "memory");
  return v;
}
__device__ __forceinline__ float4 cload4(const float* p) {
  float4 v;
  asm volatile("global_load_dwordx4 %0, %1, off sc0 sc1\n\ts_waitcnt vmcnt(0)"
               : "=v"(v) : "v"(p) : "memory");
  return v;
}
// Weight load: asm keeps program order with the a_keep moves (low arch pressure).
__device__ __forceinline__ float4 ld4(const float* p) {
  float4 v;
  asm volatile("global_load_dwordx4 %0, %1, off\n\ts_waitcnt vmcnt(0)"
               : "=v"(v) : "v"(p) : "memory");
  return v;
}
// AGPR pinning.
__device__ __forceinline__ float a_keep(float v) {
  float r;
  asm volatile("v_accvgpr_write_b32 %0, %1" : "=a"(r) : "v"(v));
  return r;
}
__device__ __forceinline__ float a_get(float a) {
  float v;
  asm volatile("v_accvgpr_read_b32 %0, %1" : "=v"(v) : "a"(a));
  return v;
}
__device__ __forceinline__ float tagctr(int step) {
  return 4.f + 8.f * (float)((step >> 3) & 1);
}
__device__ __forceinline__ bool ok4(float4 v, float c) {
  return __builtin_fabsf(v.x - c) <= 1.f && __builtin_fabsf(v.y - c) <= 1.f &&
         __builtin_fabsf(v.z - c) <= 1.f && __builtin_fabsf(v.w - c) <= 1.f;
}
__device__ __forceinline__ float4 poll4(const float* p, float c) {
  for (;;) {
    float4 v = cload4(p);
    if (ok4(v, c)) return make_float4(v.x - c, v.y - c, v.z - c, v.w - c);
  }
}

__device__ __forceinline__ void start_barrier(unsigned* slots, int wg, int tid, unsigned value) {
  __syncthreads();
  if (tid == 0) cstoreu(&slots[wg], value);
  if (tid < NWG) {
    while ((int)(cloadu(&slots[tid]) - value) < 0) __builtin_amdgcn_s_sleep(1);
  }
  __syncthreads();
}

__global__ __launch_bounds__(TPB, 2)
void rnn2_dataflow(const float* __restrict__ x,
                   const float* __restrict__ Wih0, const float* __restrict__ Whh0,
                   const float* __restrict__ bih0, const float* __restrict__ bhh0,
                   const float* __restrict__ Wih1, const float* __restrict__ Whh1,
                   const float* __restrict__ bih1, const float* __restrict__ bhh1,
                   const float* __restrict__ Wfc,  const float* __restrict__ bfc,
                   float* __restrict__ out,
                   unsigned* __restrict__ runctr, unsigned* __restrict__ slots,
                   float* __restrict__ h0s, float* __restrict__ h1s)
{
  const int wg  = blockIdx.x;
  const int tid = threadIdx.x;
  __shared__ float4 lds4[2][1024];

  const unsigned runbase = cloadu(runctr);

  if (wg < NWG0) {
    // ---------------- layer 0: 32 rows/WG, 16 threads/row ----------------
    const int cg  = tid & 15;
    const int row = wg * 32 + (tid >> 4);
    float wa[144];  // 4 f4 (Wih) + 32 f4 (Whh), pinned in AGPRs
    {
      const float* wr = Wih0 + (size_t)row * I_DIM + (cg << 2);
      #pragma unroll
      for (int k = 0; k < 4; ++k) {
        float4 v = ld4(wr + (k << 6));
        wa[4*k+0] = a_keep(v.x); wa[4*k+1] = a_keep(v.y);
        wa[4*k+2] = a_keep(v.z); wa[4*k+3] = a_keep(v.w);
      }
      const float* wr2 = Whh0 + (size_t)row * H_DIM + (cg << 2);
      #pragma unroll
      for (int k = 0; k < 32; ++k) {
        float4 v = ld4(wr2 + (k << 6));
        wa[16+4*k+0] = a_keep(v.x); wa[16+4*k+1] = a_keep(v.y);
        wa[16+4*k+2] = a_keep(v.z); wa[16+4*k+3] = a_keep(v.w);
      }
    }
    const float bias = bih0[row] + bhh0[row];

    // init: slot 0 = tagged h0_0 (=4.0), slots 1..7 invalid (0.0), owned rows
    if (tid < 256)
      cstore1(&h0s[h_off(tid >> 5, wg * 32 + (tid & 31))], (tid < 32) ? 4.f : 0.f);
    start_barrier(slots, wg, tid, runbase + 1);

    for (int s = 1; s <= L_SEQ; ++s) {
      const int p = s & 1;
      // Phase A (off the serial path): stage x_t; waves 6-7 run the throttle.
      if (tid < 64) {
        lds4[p][512 + tid] = ((const float4*)x)[(size_t)(s - 1) * 64 + tid];
      } else if (tid >= 384 && s >= 9) {
        // sentinel: every L1 WG must have published h1_{s-5} before we
        // overwrite ring slot s&7 (which holds h0_{s-8}).
        const int w1 = tid - 384;
        const float c = tagctr(s - 5);
        const float* tp = h1s + h_off((s - 5) & 7, w1 << 4);
        while (__builtin_fabsf(cload1(tp) - c) > 1.f) {}
      }
      __syncthreads();
      float a0 = 0.f, a1 = 0.f, a2 = 0.f, a3 = 0.f;
      #pragma unroll
      for (int k = 0; k < 4; ++k) {
        float4 h = lds4[p][512 + cg + 16 * k];
        a0 += a_get(wa[4*k+0]) * h.x; a1 += a_get(wa[4*k+1]) * h.y;
        a2 += a_get(wa[4*k+2]) * h.z; a3 += a_get(wa[4*k+3]) * h.w;
      }
      // Phase B (serial): poll own h0_{s-1}, then the recurrent dot.
      lds4[p][tid] = poll4(h0s + h_off((s - 1) & 7, tid << 2), tagctr(s - 1));
      __syncthreads();
      #pragma unroll
      for (int k = 0; k < 32; ++k) {
        float4 h = lds4[p][cg + 16 * k];
        a0 += a_get(wa[16+4*k+0]) * h.x; a1 += a_get(wa[16+4*k+1]) * h.y;
        a2 += a_get(wa[16+4*k+2]) * h.z; a3 += a_get(wa[16+4*k+3]) * h.w;
      }
      float acc = (a0 + a1) + (a2 + a3);
      acc += __shfl_xor(acc, 1);
      acc += __shfl_xor(acc, 2);
      acc += __shfl_xor(acc, 4);
      acc += __shfl_xor(acc, 8);
      if (cg == 0)
        cstore1(&h0s[h_off(s & 7, row)], tanhf(acc + bias) + tagctr(s));
    }

    if (wg == 0) {
      // final FC: sigmoid(h1_8192 . Wfc + bfc); slot 0, ctr 4 (safe: throttle
      // guarantees L1 >= 8187, so slot 0 holds 8184 (ctr 12, invalid) or 8192).
      float4 hv = poll4(h1s + h_off(0, tid << 2), tagctr(L_SEQ));
      float4 wv = ((const float4*)Wfc)[tid];
      float pz = hv.x * wv.x + hv.y * wv.y + hv.z * wv.z + hv.w * wv.w;
      pz += __shfl_xor(pz, 1);  pz += __shfl_xor(pz, 2);  pz += __shfl_xor(pz, 4);
      pz += __shfl_xor(pz, 8);  pz += __shfl_xor(pz, 16); pz += __shfl_xor(pz, 32);
      float* lred = (float*)&lds4[0][0];
      __syncthreads();
      if ((tid & 63) == 0) lred[tid >> 6] = pz;
      __syncthreads();
      if (tid == 0) {
        float z = bfc[0];
        #pragma unroll
        for (int w = 0; w < TPB / 64; ++w) z += lred[w];
        out[0] = 1.f / (1.f + expf(-z));
        cstoreu(runctr, runbase + 1);
      }
    }
  } else {
    // ---------------- layer 1: 16 rows/WG, 32 threads/row ----------------
    const int cg  = tid & 31;
    const int wgl = wg - NWG0;
    const int row = wgl * 16 + (tid >> 5);
    float wa[128];  // 16 f4 (Wih1) + 16 f4 (Whh1), pinned in AGPRs
    {
      const float* wr = Wih1 + (size_t)row * H_DIM + (cg << 2);
      #pragma unroll
      for (int k = 0; k < 16; ++k) {
        float4 v = ld4(wr + (k << 7));
        wa[4*k+0] = a_keep(v.x); wa[4*k+1] = a_keep(v.y);
        wa[4*k+2] = a_keep(v.z); wa[4*k+3] = a_keep(v.w);
      }
      const float* wr2 = Whh1 + (size_t)row * H_DIM + (cg << 2);
      #pragma unroll
      for (int k = 0; k < 16; ++k) {
        float4 v = ld4(wr2 + (k << 7));
        wa[64+4*k+0] = a_keep(v.x); wa[64+4*k+1] = a_keep(v.y);
        wa[64+4*k+2] = a_keep(v.z); wa[64+4*k+3] = a_keep(v.w);
      }
    }
    const float bias = bih1[row] + bhh1[row];

    if (tid < 128)
      cstore1(&h1s[h_off(tid >> 4, wgl * 16 + (tid & 15))], (tid < 16) ? 4.f : 0.f);
    start_barrier(slots, wg, tid, runbase + 1);

    for (int t = 1; t <= L_SEQ; ++t) {  // h1_t = tanh(Wih1 h0_t + Whh1 h1_{t-1} + b)
      const int p = t & 1;
      // Phase A: h0_t is ready early (L0 runs ahead); compute the ih partial.
      lds4[p][tid] = poll4(h0s + h_off(t & 7, tid << 2), tagctr(t));
      __syncthreads();
      float a0 = 0.f, a1 = 0.f, a2 = 0.f, a3 = 0.f;
      #pragma unroll
      for (int k = 0; k < 16; ++k) {
        float4 h = lds4[p][cg + 32 * k];
        a0 += a_get(wa[4*k+0]) * h.x; a1 += a_get(wa[4*k+1]) * h.y;
        a2 += a_get(wa[4*k+2]) * h.z; a3 += a_get(wa[4*k+3]) * h.w;
      }
      // Phase B (serial): poll h1_{t-1}, recurrent dot, publish.
      lds4[p][512 + tid] = poll4(h1s + h_off((t - 1) & 7, tid << 2), tagctr(t - 1));
      __syncthreads();
      #pragma unroll
      for (int k = 0; k < 16; ++k) {
        float4 h = lds4[p][512 + cg + 32 * k];
        a0 += a_get(wa[64+4*k+0]) * h.x; a1 += a_get(wa[64+4*k+1]) * h.y;
        a2 += a_get(wa[64+4*k+2]) * h.z; a3 += a_get(wa[64+4*k+3]) * h.w;
      }
      float acc = (a0 + a1) + (a2 + a3);
      acc += __shfl_xor(acc, 1);
      acc += __shfl_xor(acc, 2);
      acc += __shfl_xor(acc, 4);
      acc += __shfl_xor(acc, 8);
      acc += __shfl_xor(acc, 16);
      if (cg == 0)
        cstore1(&h1s[h_off(t & 7, row)], tanhf(acc + bias) + tagctr(t));
    }
  }
}

extern "C" void kernel_launch(void* const* d_in, const int* in_sizes, int n_in,
                              void* d_out, int out_size, void* d_ws, size_t ws_size,
                              hipStream_t stream) {
  const float* xx   = (const float*)d_in[0];
  const float* Wih0 = (const float*)d_in[1];
  const float* Whh0 = (const float*)d_in[2];
  const float* bih0 = (const float*)d_in[3];
  const float* bhh0 = (const float*)d_in[4];
  const float* Wih1 = (const float*)d_in[5];
  const float* Whh1 = (const float*)d_in[6];
  const float* bih1 = (const float*)d_in[7];
  const float* bhh1 = (const float*)d_in[8];
  const float* Wfc  = (const float*)d_in[9];
  const float* bfc  = (const float*)d_in[10];

  unsigned* runctr = (unsigned*)d_ws;
  unsigned* slots  = (unsigned*)((char*)d_ws + 256);
  float* h0s       = (float*)((char*)d_ws + 4096);
  float* h1s       = (float*)((char*)d_ws + 4096 + 8 * 8192 * sizeof(float));

  rnn2_dataflow<<<dim3(NWG), dim3(TPB), 0, stream>>>(
      xx, Wih0, Whh0, bih0, bhh0, Wih1, Whh1, bih1, bhh1, Wfc, bfc,
      (float*)d_out, runctr, slots, h0s, h1s);
}

// Round 6
// 42227.097 us; speedup vs baseline: 1.2857x; 1.2857x over previous
//
#include <hip/hip_runtime.h>
#include <math.h>

#define L_SEQ 8192
#define I_DIM 256
#define H_DIM 2048
#define NWG0  64          // layer-0: 64 WGs x 32 rows (16 thr/row)
#define NWG1  128         // layer-1: 128 WGs x 16 rows (32 thr/row)
#define NWG   (NWG0 + NWG1)
#define TPB   512
#define RD    16          // h ring depth
#define THR   13          // L0 throttle lag (margin 2 vs RD, see proof below)

// ws layout (bytes): [0] runctr | [256) f0[64] | [1024) f1[128] | [2048) bslots[192]
//   [4096) h0 ring RD*2048 f32 (contiguous) | [135168) h1 ring RD*2048 f32
//
// Protocol: producer WG stores its h rows (sc0sc1, tagged value = h + ctr(step),
// ctr = 4 + 8*((step>>4)&1)), then tid0 stores flag[wg] = runbase*16384 + step.
// Consumers spin on the FLAG VECTOR only (tiny traffic; kills the round-4 poll
// storm), then issue ONE tagged bulk load of the h vector; the tag check absorbs
// the tid0-flag vs other-wave-store skew (rare respins). Ring safety:
//  - L0/L1 peers stay within 1 step (each validates full prior vector via flags).
//  - L1 <= L0 (consumes h0_t only after f0 >= t); L0 <= minL1 + THR + 1 via the
//    f1 throttle. Overwrite of slot s&15 (holding step s-16) is safe since all
//    consumers are >= s-15 (margin 2). Same-tag aliasing needs lag >= 32: unreachable.
//  - All 16 slots of owned rows re-invalidated (0.0f) each run before the start
//    barrier; 0xAA poison (-3e-13) and 0.0f fail both tag windows [3,5]/[11,13].
// Weights: asm-opaque loads (no remat) pinned in arch VGPRs; launch_bounds(512,1)
// gives the allocator the full 256-reg/wave envelope (8 waves must fit a CU).

__device__ __forceinline__ void cstore1(float* p, float v) {
  asm volatile("global_store_dword %0, %1, off sc0 sc1" :: "v"(p), "v"(v) : "memory");
}
__device__ __forceinline__ void cstoreu(unsigned* p, unsigned v) {
  asm volatile("global_store_dword %0, %1, off sc0 sc1" :: "v"(p), "v"(v) : "memory");
}
__device__ __forceinline__ unsigned cloadu(const unsigned* p) {
  unsigned v;
  asm volatile("global_load_dword %0, %1, off sc0 sc1\n\ts_waitcnt vmcnt(0)"
               : "=v"(v) : "v"(p) : "memory");
  return v;
}
__device__ __forceinline__ float4 cload4(const float* p) {
  float4 v;
  asm volatile("global_load_dwordx4 %0, %1, off sc0 sc1\n\ts_waitcnt vmcnt(0)"
               : "=v"(v) : "v"(p) : "memory");
  return v;
}
__device__ __forceinline__ void cload4x2(const float* p0, const float* p1, float4& a, float4& b) {
  asm volatile("global_load_dwordx4 %0, %2, off sc0 sc1\n\t"
               "global_load_dwordx4 %1, %3, off sc0 sc1\n\t"
               "s_waitcnt vmcnt(0)"
               : "=&v"(a), "=&v"(b) : "v"(p0), "v"(p1) : "memory");
}
// Weight load: opaque to LLVM -> cannot be rematerialized; stays in VGPRs.
__device__ __forceinline__ float4 ld4(const float* p) {
  float4 v;
  asm volatile("global_load_dwordx4 %0, %1, off\n\ts_waitcnt vmcnt(0)"
               : "=v"(v) : "v"(p) : "memory");
  return v;
}
__device__ __forceinline__ float dot4(float4 a, float4 b) {
  return a.x * b.x + a.y * b.y + a.z * b.z + a.w * b.w;
}
__device__ __forceinline__ float tagc(int step) {
  return 4.f + 8.f * (float)((step >> 4) & 1);
}
__device__ __forceinline__ bool ok4(float4 v, float c) {
  return __builtin_fabsf(v.x - c) <= 1.f && __builtin_fabsf(v.y - c) <= 1.f &&
         __builtin_fabsf(v.z - c) <= 1.f && __builtin_fabsf(v.w - c) <= 1.f;
}
__device__ __forceinline__ float4 poll4(const float* p, float c) {
  for (;;) {
    float4 v = cload4(p);
    if (ok4(v, c)) return make_float4(v.x - c, v.y - c, v.z - c, v.w - c);
  }
}
__device__ __forceinline__ void poll4x2(const float* p0, float c0,
                                        const float* p1, float c1,
                                        float4& a, float4& b) {
  for (;;) {
    float4 u, v;
    cload4x2(p0, p1, u, v);
    if (ok4(u, c0) && ok4(v, c1)) {
      a = make_float4(u.x - c0, u.y - c0, u.z - c0, u.w - c0);
      b = make_float4(v.x - c1, v.y - c1, v.z - c1, v.w - c1);
      return;
    }
  }
}
__device__ __forceinline__ void flagwait(const unsigned* p, unsigned want) {
  while ((int)(cloadu(p) - want) < 0) {}
}

__device__ __forceinline__ void start_barrier(unsigned* bslots, int wg, int tid, unsigned value) {
  asm volatile("s_waitcnt vmcnt(0)" ::: "memory");
  __syncthreads();
  if (tid == 0) cstoreu(&bslots[wg], value);
  if (tid < NWG) {
    while ((int)(cloadu(&bslots[tid]) - value) < 0) __builtin_amdgcn_s_sleep(1);
  }
  __syncthreads();
}

__global__ __launch_bounds__(TPB, 1)
void rnn2_flags(const float* __restrict__ x,
                const float* __restrict__ Wih0, const float* __restrict__ Whh0,
                const float* __restrict__ bih0, const float* __restrict__ bhh0,
                const float* __restrict__ Wih1, const float* __restrict__ Whh1,
                const float* __restrict__ bih1, const float* __restrict__ bhh1,
                const float* __restrict__ Wfc,  const float* __restrict__ bfc,
                float* __restrict__ out,
                unsigned* __restrict__ runctr, unsigned* __restrict__ f0,
                unsigned* __restrict__ f1, unsigned* __restrict__ bslots,
                float* __restrict__ h0s, float* __restrict__ h1s)
{
  const int wg  = blockIdx.x;
  const int tid = threadIdx.x;
  __shared__ float4 lds4[2][1024];

  const unsigned runbase = cloadu(runctr);
  const unsigned base = runbase * 16384u;

  if (wg < NWG0) {
    // ---------------- layer 0: 32 rows/WG, 16 threads/row ----------------
    const int cg  = tid & 15;
    const int row = wg * 32 + (tid >> 4);
    float4 wihr[4], whhr[32];
    {
      const float* wr = Wih0 + (size_t)row * I_DIM + (cg << 2);
      #pragma unroll
      for (int k = 0; k < 4; ++k) wihr[k] = ld4(wr + (k << 6));
      const float* wr2 = Whh0 + (size_t)row * H_DIM + (cg << 2);
      #pragma unroll
      for (int k = 0; k < 32; ++k) whhr[k] = ld4(wr2 + (k << 6));
    }
    const float bias = bih0[row] + bhh0[row];

    // re-init all RD slots of owned rows: slot 0 = tagged h0_0, rest invalid
    { int sl = tid >> 5; int r = wg * 32 + (tid & 31);
      cstore1(&h0s[sl * H_DIM + r], (sl == 0) ? 4.f : 0.f); }
    start_barrier(bslots, wg, tid, runbase + 1);

    for (int s = 1; s <= L_SEQ; ++s) {
      const int p = s & 1;
      if (tid < 64) {                       // gate: all L0 flags >= s-1
        if (s > 1) flagwait(&f0[tid], base + (unsigned)(s - 1));
      } else if (tid < 128) {               // throttle: all L1 flags >= s-THR
        if (s > THR) {
          const unsigned want = base + (unsigned)(s - THR);
          flagwait(&f1[(tid - 64) * 2], want);
          flagwait(&f1[(tid - 64) * 2 + 1], want);
        }
      } else if (tid < 192) {               // stage x_t
        lds4[p][512 + (tid - 128)] = ((const float4*)x)[(size_t)(s - 1) * 64 + (tid - 128)];
      }
      __syncthreads();
      lds4[p][tid] = poll4(h0s + ((s - 1) & (RD - 1)) * H_DIM + (tid << 2), tagc(s - 1));
      __syncthreads();
      float a0 = 0.f, a1 = 0.f, a2 = 0.f, a3 = 0.f;
      #pragma unroll
      for (int k = 0; k < 4; ++k) {
        float4 h = lds4[p][512 + cg + 16 * k];
        a0 += wihr[k].x * h.x; a1 += wihr[k].y * h.y;
        a2 += wihr[k].z * h.z; a3 += wihr[k].w * h.w;
      }
      #pragma unroll
      for (int k = 0; k < 32; ++k) {
        float4 h = lds4[p][cg + 16 * k];
        a0 += whhr[k].x * h.x; a1 += whhr[k].y * h.y;
        a2 += whhr[k].z * h.z; a3 += whhr[k].w * h.w;
      }
      float acc = (a0 + a1) + (a2 + a3);
      acc += __shfl_xor(acc, 1);
      acc += __shfl_xor(acc, 2);
      acc += __shfl_xor(acc, 4);
      acc += __shfl_xor(acc, 8);
      if (cg == 0)
        cstore1(&h0s[(s & (RD - 1)) * H_DIM + row], tanhf(acc + bias) + tagc(s));
      if (tid == 0) cstoreu(&f0[wg], base + (unsigned)s);
    }

    if (wg == 0) {
      // final FC: sigmoid(h1_8192 . Wfc + bfc); slot 8192&15 = 0, ctr 4
      if (tid < 64) {
        const unsigned want = base + (unsigned)L_SEQ;
        flagwait(&f1[tid * 2], want);
        flagwait(&f1[tid * 2 + 1], want);
      }
      __syncthreads();
      float4 hv = poll4(h1s + (L_SEQ & (RD - 1)) * H_DIM + (tid << 2), tagc(L_SEQ));
      float4 wv = ((const float4*)Wfc)[tid];
      float pz = dot4(hv, wv);
      pz += __shfl_xor(pz, 1);  pz += __shfl_xor(pz, 2);  pz += __shfl_xor(pz, 4);
      pz += __shfl_xor(pz, 8);  pz += __shfl_xor(pz, 16); pz += __shfl_xor(pz, 32);
      float* lred = (float*)&lds4[0][0];
      __syncthreads();
      if ((tid & 63) == 0) lred[tid >> 6] = pz;
      __syncthreads();
      if (tid == 0) {
        float z = bfc[0];
        #pragma unroll
        for (int w = 0; w < TPB / 64; ++w) z += lred[w];
        out[0] = 1.f / (1.f + expf(-z));
        cstoreu(runctr, runbase + 1);
      }
    }
  } else {
    // ---------------- layer 1: 16 rows/WG, 32 threads/row ----------------
    const int cg  = tid & 31;
    const int wgl = wg - NWG0;
    const int row = wgl * 16 + (tid >> 5);
    float4 wihr[16], whhr[16];
    {
      const float* wr = Wih1 + (size_t)row * H_DIM + (cg << 2);
      #pragma unroll
      for (int k = 0; k < 16; ++k) wihr[k] = ld4(wr + (k << 7));
      const float* wr2 = Whh1 + (size_t)row * H_DIM + (cg << 2);
      #pragma unroll
      for (int k = 0; k < 16; ++k) whhr[k] = ld4(wr2 + (k << 7));
    }
    const float bias = bih1[row] + bhh1[row];

    if (tid < 256) { int sl = tid >> 4; int r = wgl * 16 + (tid & 15);
      cstore1(&h1s[sl * H_DIM + r], (sl == 0) ? 4.f : 0.f); }
    start_barrier(bslots, wg, tid, runbase + 1);

    for (int t = 1; t <= L_SEQ; ++t) {  // h1_t = tanh(Wih1 h0_t + Whh1 h1_{t-1} + b)
      const int p = t & 1;
      if (tid < 64) {                       // gate: all L0 flags >= t
        flagwait(&f0[tid], base + (unsigned)t);
      } else if (tid < 128) {               // gate: all L1 flags >= t-1
        if (t > 1) {
          const unsigned want = base + (unsigned)(t - 1);
          flagwait(&f1[(tid - 64) * 2], want);
          flagwait(&f1[(tid - 64) * 2 + 1], want);
        }
      }
      __syncthreads();
      float4 a, b;
      poll4x2(h0s + (t & (RD - 1)) * H_DIM + (tid << 2), tagc(t),
              h1s + ((t - 1) & (RD - 1)) * H_DIM + (tid << 2), tagc(t - 1), a, b);
      lds4[p][tid] = a;
      lds4[p][512 + tid] = b;
      __syncthreads();
      float a0 = 0.f, a1 = 0.f, a2 = 0.f, a3 = 0.f;
      #pragma unroll
      for (int k = 0; k < 16; ++k) {
        float4 h = lds4[p][cg + 32 * k];
        a0 += wihr[k].x * h.x; a1 += wihr[k].y * h.y;
        a2 += wihr[k].z * h.z; a3 += wihr[k].w * h.w;
      }
      #pragma unroll
      for (int k = 0; k < 16; ++k) {
        float4 h = lds4[p][512 + cg + 32 * k];
        a0 += whhr[k].x * h.x; a1 += whhr[k].y * h.y;
        a2 += whhr[k].z * h.z; a3 += whhr[k].w * h.w;
      }
      float acc = (a0 + a1) + (a2 + a3);
      acc += __shfl_xor(acc, 1);
      acc += __shfl_xor(acc, 2);
      acc += __shfl_xor(acc, 4);
      acc += __shfl_xor(acc, 8);
      acc += __shfl_xor(acc, 16);
      if (cg == 0)
        cstore1(&h1s[(t & (RD - 1)) * H_DIM + row], tanhf(acc + bias) + tagc(t));
      if (tid == 0) cstoreu(&f1[wgl], base + (unsigned)t);
    }
  }
}

extern "C" void kernel_launch(void* const* d_in, const int* in_sizes, int n_in,
                              void* d_out, int out_size, void* d_ws, size_t ws_size,
                              hipStream_t stream) {
  const float* xx   = (const float*)d_in[0];
  const float* Wih0 = (const float*)d_in[1];
  const float* Whh0 = (const float*)d_in[2];
  const float* bih0 = (const float*)d_in[3];
  const float* bhh0 = (const float*)d_in[4];
  const float* Wih1 = (const float*)d_in[5];
  const float* Whh1 = (const float*)d_in[6];
  const float* bih1 = (const float*)d_in[7];
  const float* bhh1 = (const float*)d_in[8];
  const float* Wfc  = (const float*)d_in[9];
  const float* bfc  = (const float*)d_in[10];

  unsigned* runctr = (unsigned*)d_ws;
  unsigned* f0     = (unsigned*)((char*)d_ws + 256);
  unsigned* f1     = (unsigned*)((char*)d_ws + 1024);
  unsigned* bslots = (unsigned*)((char*)d_ws + 2048);
  float* h0s       = (float*)((char*)d_ws + 4096);
  float* h1s       = (float*)((char*)d_ws + 4096 + RD * H_DIM * sizeof(float));

  rnn2_flags<<<dim3(NWG), dim3(TPB), 0, stream>>>(
      xx, Wih0, Whh0, bih0, bhh0, Wih1, Whh1, bih1, bhh1, Wfc, bfc,
      (float*)d_out, runctr, f0, f1, bslots, h0s, h1s);
}